// Round 4
// baseline (193.210 us; speedup 1.0000x reference)
//
#include <hip/hip_runtime.h>

typedef _Float16 half8_t __attribute__((ext_vector_type(8)));
typedef _Float16 half4_t __attribute__((ext_vector_type(4)));
typedef float floatx4 __attribute__((ext_vector_type(4)));

#define BB 8
#define CC 64
#define HH 128
#define WW 256
#define DD 64
#define NROW 2            // tasks per block
#define GRID 1024         // 4 blocks per CU; NROW*GRID == 2048 half-row tasks
#define OPITCH 36         // per-wave Ob pitch (floats): bank=(4d+wl)&31, 2/bank

// out[b,d,h,w] = (1/64) sum_c L[b,c,h,w] * R[b,c,h,w-d], 0 where w<d.
// Banded Gram via mfma_f32_16x16x32_f16 (d = 64-16u+n-m algebra, verified R3+).
// R7: coalesced LDS-transposed epilogue -> 63.5us, occupancy 29%, HBM 26%.
// R8: 1-wave blocks regressed (73us, occ 16.7%): LDS granularity wasted,
//     too few co-resident waves to hide per-wave serial latency.
// R9: depth via 4 independent 4-wave blocks/CU. Task = 128-w half-row:
//     Lb[128][64]f16 16K + Rb[192][64]f16 24K = 40KB -> 4 blocks/CU (160KB).
//     Barriers 4 -> 3: output transpose buffer is now WAVE-PRIVATE
//     (Obw[64][36] overlay; each wave stores only its own 32-w slice, every
//     d hit exactly once), so the pre-store barrier is just lgkmcnt.
//     Staging-write bank fix: col swizzle extended to cg^(j&7)^((j>>3)&7)
//     (write side spreads all 8 bank-quads per 16-lane beat; read side
//     recomputes col per fragment row, stays 2-lane/bank).
__global__ __launch_bounds__(256, 4)
void corr_volume_mfma(const float* __restrict__ left,
                      const float* __restrict__ right,
                      float* __restrict__ out) {
    // 40 KiB arena: staging Lb(16K)+Rb(24K); epilogue overlays 4x9216B Obw.
    __shared__ alignas(16) unsigned char smem[40960];
    _Float16* const Lb = (_Float16*)smem;            // [128][64]
    _Float16* const Rb = (_Float16*)(smem + 16384);  // [192][64], row j: w'=W0-64+j

    const int tid  = threadIdx.x;
    const int lane = tid & 63;
    const int wv   = tid >> 6;                        // wave 0..3
    float* const Obw = (float*)smem + wv * (DD * OPITCH);   // wave-private 9216 B

    // XCD-affine swizzle: XCD k gets contiguous task range; the two halves
    // of a row run on adjacent slots of the same XCD (R-band overlap -> L2).
    const int swz = (blockIdx.x & 7) * 128 + (blockIdx.x >> 3);
    const int hf  = swz & 1;                          // fixed half per block
    const int W0  = hf << 7;                          // tile base w: 0 or 128

    const size_t chanStride = (size_t)HH * WW;        // 32768

    const int cg  = tid >> 5;          // channel group (8 ch) for L / R-A
    const int wq  = (tid & 31) * 4;    // w-quad 0..124
    const int cg4 = tid >> 4;          // channel group (4 ch) for R-B
    const int wq4 = (tid & 15) * 4;    // w-quad 0..60

    float4 lv[8], ra[8], rb4[4];

    // Prologue: issue task-0 loads.
    {
        const int bh = swz >> 1;
        const size_t rowBase = (size_t)(bh >> 7) * CC * chanStride
                             + (size_t)(bh & 127) * WW;
        const float* lp = left  + rowBase + (size_t)(cg * 8) * chanStride + W0 + wq;
        const float* rp = right + rowBase + (size_t)(cg * 8) * chanStride + W0 + wq;
        #pragma unroll
        for (int c = 0; c < 8; ++c) lv[c] = *(const float4*)(lp + (size_t)c * chanStride);
        #pragma unroll
        for (int c = 0; c < 8; ++c) ra[c] = *(const float4*)(rp + (size_t)c * chanStride);
        if (hf) {   // rows 0..63: w' = W0-64+j in [64,128), only valid when W0=128
            const float* rq = right + rowBase + (size_t)(cg4 * 4) * chanStride + (W0 - 64) + wq4;
            #pragma unroll
            for (int c = 0; c < 4; ++c) rb4[c] = *(const float4*)(rq + (size_t)c * chanStride);
        }
    }

    const int n  = lane & 15;          // MFMA col (w) / A row
    const int qd = lane >> 4;          // quad
    const int wbase = wv * 32;         // wave's local w range
    const float scale = 1.0f / 64.0f;

    #pragma unroll
    for (int k = 0; k < NROW; ++k) {
        const int tsk = swz + k * GRID;
        const int bh  = tsk >> 1;
        const int b   = bh >> 7;
        const int h   = bh & 127;

        __syncthreads();   // A: prior task's Ob reads done; prefetch drained

        // half-0 blocks: re-zero pad rows 0..63 (Ob overlay clobbers them)
        if (!hf) {
            half8_t z = {0, 0, 0, 0, 0, 0, 0, 0};
            *(half8_t*)&Rb[tid * 16]     = z;
            *(half8_t*)&Rb[tid * 16 + 8] = z;
        }

        // Transpose-stage regs -> LDS (f32 -> f16).
        {
            const float* lf = (const float*)lv;
            const float* rf = (const float*)ra;
            #pragma unroll
            for (int s = 0; s < 4; ++s) {
                const int jl = wq + s;
                const int cl = (cg ^ (jl & 7) ^ ((jl >> 3) & 7)) * 8;
                const int jr = jl + 64;
                const int cr = (cg ^ (jr & 7) ^ ((jr >> 3) & 7)) * 8;
                half8_t vL, vR;
                #pragma unroll
                for (int c = 0; c < 8; ++c) {
                    vL[c] = (_Float16)lf[c * 4 + s];
                    vR[c] = (_Float16)rf[c * 4 + s];
                }
                *(half8_t*)&Lb[jl * 64 + cl] = vL;
                *(half8_t*)&Rb[jr * 64 + cr] = vR;
            }
            if (hf) {
                const float* rg = (const float*)rb4;
                #pragma unroll
                for (int s = 0; s < 4; ++s) {
                    const int j  = wq4 + s;
                    const int cb = ((cg4 >> 1) ^ (j & 7) ^ ((j >> 3) & 7)) * 8
                                 + (cg4 & 1) * 4;
                    half4_t v;
                    #pragma unroll
                    for (int c = 0; c < 4; ++c) v[c] = (_Float16)rg[c * 4 + s];
                    *(half4_t*)&Rb[j * 64 + cb] = v;
                }
            }
        }
        __syncthreads();   // B: tiles staged

        // ---------------- MFMA ----------------
        floatx4 acc[2][5];
        #pragma unroll
        for (int t = 0; t < 2; ++t)
            #pragma unroll
            for (int u = 0; u < 5; ++u)
                #pragma unroll
                for (int r = 0; r < 4; ++r)
                    acc[t][u][r] = 0.0f;

        #pragma unroll
        for (int kk = 0; kk < 2; ++kk) {
            const int xb = (kk * 4 + qd) ^ (n & 7);
            half8_t bfrag[2], afrag[6];
            #pragma unroll
            for (int t = 0; t < 2; ++t) {
                const int j = wbase + t * 16 + n;
                bfrag[t] = *(const half8_t*)&Lb[j * 64 + (xb ^ ((j >> 3) & 7)) * 8];
            }
            #pragma unroll
            for (int a = 0; a < 6; ++a) {
                const int j = wbase + a * 16 + n;
                afrag[a] = *(const half8_t*)&Rb[j * 64 + (xb ^ ((j >> 3) & 7)) * 8];
            }
            #pragma unroll
            for (int t = 0; t < 2; ++t)
                #pragma unroll
                for (int u = 0; u < 5; ++u)
                    acc[t][u] = __builtin_amdgcn_mfma_f32_16x16x32_f16(
                        afrag[t + u], bfrag[t], acc[t][u], 0, 0, 0);
        }
        __syncthreads();   // C: all fragment reads done; Lb/Rb dead -> Obw

        // acc -> wave-private Obw[d][wl]. d = 64-16u+n-m, m = qd*4+r.
        #pragma unroll
        for (int t = 0; t < 2; ++t) {
            const int wl = t * 16 + n;
            #pragma unroll
            for (int u = 0; u < 5; ++u) {
                #pragma unroll
                for (int r = 0; r < 4; ++r) {
                    const int d = 64 - 16 * u + n - (qd * 4 + r);
                    if (d >= 0 && d < DD) {
                        Obw[d * OPITCH + wl] = acc[t][u][r] * scale;
                    }
                }
            }
        }

        // Prefetch next task — in flight through the store phase, drained at A.
        if (k + 1 < NROW) {
            const int bh2 = (swz + (k + 1) * GRID) >> 1;
            const size_t rowBase2 = (size_t)(bh2 >> 7) * CC * chanStride
                                  + (size_t)(bh2 & 127) * WW;
            const float* lp = left  + rowBase2 + (size_t)(cg * 8) * chanStride + W0 + wq;
            const float* rp = right + rowBase2 + (size_t)(cg * 8) * chanStride + W0 + wq;
            #pragma unroll
            for (int c = 0; c < 8; ++c) lv[c] = *(const float4*)(lp + (size_t)c * chanStride);
            #pragma unroll
            for (int c = 0; c < 8; ++c) ra[c] = *(const float4*)(rp + (size_t)c * chanStride);
            if (hf) {
                const float* rq = right + rowBase2 + (size_t)(cg4 * 4) * chanStride + (W0 - 64) + wq4;
                #pragma unroll
                for (int c = 0; c < 4; ++c) rb4[c] = *(const float4*)(rq + (size_t)c * chanStride);
            }
        }

        // Wave-local coalesced stores: no barrier needed (own Obw only;
        // compiler inserts lgkmcnt between ds_write and ds_read).
        // Each instr: 8 d-rows x 128 B contiguous (full 64B lines).
        #pragma unroll
        for (int i = 0; i < 8; ++i) {
            const int d  = i * 8 + (lane >> 3);
            const int wl = (lane & 7) * 4;
            const float4 v = *(const float4*)&Obw[d * OPITCH + wl];
            *(float4*)&out[(((size_t)b * DD + d) * HH + h) * WW + W0 + wbase + wl] = v;
        }
    }
}

extern "C" void kernel_launch(void* const* d_in, const int* in_sizes, int n_in,
                              void* d_out, int out_size, void* d_ws, size_t ws_size,
                              hipStream_t stream) {
    const float* left  = (const float*)d_in[0];
    const float* right = (const float*)d_in[1];
    float* out = (float*)d_out;

    dim3 grid(GRID);    // 1024 blocks = 4 per CU, each pipelines NROW tasks
    dim3 block(256);
    corr_volume_mfma<<<grid, block, 0, stream>>>(left, right, out);
}

// Round 5
// 176.201 us; speedup vs baseline: 1.0965x; 1.0965x over previous
//
#include <hip/hip_runtime.h>

typedef _Float16 half8 __attribute__((ext_vector_type(8)));
typedef float floatx4 __attribute__((ext_vector_type(4)));

#define BB 8
#define CC 64
#define HH 128
#define WW 256
#define DD 64
#define NROW 2            // (b,h) rows per block
#define GRID 512          // 2 blocks per CU; NROW*GRID == BB*HH
#define OPITCH 260        // Ob row pitch (floats): bank=(4d+w)&31 -> 2 lanes/bank

// LDS-only barrier: __syncthreads() emits s_waitcnt vmcnt(0) lgkmcnt(0)
// before s_barrier, draining prefetch loads AND output stores at every
// barrier. All cross-wave data here flows through LDS, so lgkmcnt(0) is
// sufficient; register-prefetch consumption is ordered per-thread by
// compiler-inserted counted vmcnt, and stores need no cross-wave visibility.
#define BAR() asm volatile("s_waitcnt lgkmcnt(0)\n\ts_barrier" ::: "memory")

// out[b,d,h,w] = (1/64) sum_c L[b,c,h,w] * R[b,c,h,w-d], 0 where w<d.
// Banded Gram via mfma_f32_16x16x32_f16 (d = 64-16u+n-m algebra).
// R7: coalesced LDS-transposed epilogue (WRITE_SIZE == out size, RFO gone):
//     63.5us. R8 (1-wave blocks) and R9 (4x 4-wave blocks, wave-private Ob)
//     both regressed — R9 also showed +39% WRITE_SIZE from 128B-scattered
//     stores; full 1KB-contiguous store rows are the right epilogue.
// R10: barriers become lgkmcnt-only (BAR above). Previously all 4 barriers
//     per row drained vmcnt(0) across 8 lockstep waves (R6: a 2nd
//     phase-locked block didn't help because it stalls at the same time).
//     Now: stores drain lazily under the next row's load phase; prefetch
//     loads issued after barrier B stay in flight through MFMA+Ob+store
//     and are waited per-thread (counted) only at the cvt that uses them.
__global__ __launch_bounds__(512, 2)
void corr_volume_mfma(const float* __restrict__ left,
                      const float* __restrict__ right,
                      float* __restrict__ out) {
    // 72 KiB arena: phase 1 = Lb[256*64] (32K) + Rb[320*64] (40K) halves;
    // phase 2 (epilogue) overlays Ob[64][OPITCH] floats (66,560 B).
    __shared__ alignas(16) unsigned char smem[73728];
    _Float16* const Lb = (_Float16*)smem;
    _Float16* const Rb = (_Float16*)(smem + 32768);
    float*    const Ob = (float*)smem;

    const int tid  = threadIdx.x;
    const int lane = tid & 63;
    const int wv   = tid >> 6;          // wave 0..7
    const int sw   = lane * 4;          // staged w rows sw..sw+3
    const int cg   = wv;                // staged channel group cg*8..cg*8+7

    const size_t chanStride = (size_t)HH * WW;      // 32768

    float4 lv[8], rv[8];

    // Prologue: issue row-0 loads immediately.
    {
        const int bh = blockIdx.x;
        const size_t rowBase = (size_t)(bh >> 7) * CC * chanStride
                             + (size_t)(bh & 127) * WW;
        const float* lp = left  + rowBase + (size_t)(cg * 8) * chanStride + sw;
        const float* rp = right + rowBase + (size_t)(cg * 8) * chanStride + sw;
        #pragma unroll
        for (int c = 0; c < 8; ++c) {
            lv[c] = *(const float4*)(lp + (size_t)c * chanStride);
            rv[c] = *(const float4*)(rp + (size_t)c * chanStride);
        }
    }

    const int n = lane & 15;            // MFMA col (w) / A row
    const int q = lane >> 4;            // quad
    const int wbase = wv * 32;          // this wave's w range
    const float scale = 1.0f / 64.0f;

    #pragma unroll
    for (int k = 0; k < NROW; ++k) {
        const int bh = blockIdx.x + k * GRID;
        const int b  = bh >> 7;
        const int h  = bh & 127;

        BAR();   // A: prior row's Ob ds_reads done (k=0: orders nothing)

        // Re-zero the w'<0 pad rows (Ob overlay clobbers them every row).
        {
            half8 z = {0, 0, 0, 0, 0, 0, 0, 0};
            *(half8*)&Rb[tid * 8] = z;
        }

        // Transpose 8c x 4w from regs -> LDS. Compiler inserts the counted
        // vmcnt wait for this row's loads right here (per-thread, no
        // cross-wave drain); last row's stores remain in flight.
        {
            const float* lf = (const float*)lv;
            const float* rf = (const float*)rv;
            #pragma unroll
            for (int s = 0; s < 4; ++s) {
                const int w   = sw + s;
                const int col = (cg ^ (w & 7)) * 8;
                half8 lh, rh;
                #pragma unroll
                for (int c = 0; c < 8; ++c) {
                    lh[c] = (_Float16)lf[c * 4 + s];
                    rh[c] = (_Float16)rf[c * 4 + s];
                }
                *(half8*)&Lb[w * 64 + col]        = lh;
                *(half8*)&Rb[(w + 64) * 64 + col] = rh;
            }
        }
        BAR();   // B: tiles staged (lgkmcnt-only)

        // Prefetch next row — stays in flight through MFMA+Ob+stores and
        // across barriers (no vmcnt drain anywhere).
        if (k + 1 < NROW) {
            const int bh2 = blockIdx.x + (k + 1) * GRID;
            const size_t rowBase2 = (size_t)(bh2 >> 7) * CC * chanStride
                                  + (size_t)(bh2 & 127) * WW;
            const float* lp = left  + rowBase2 + (size_t)(cg * 8) * chanStride + sw;
            const float* rp = right + rowBase2 + (size_t)(cg * 8) * chanStride + sw;
            #pragma unroll
            for (int c = 0; c < 8; ++c) {
                lv[c] = *(const float4*)(lp + (size_t)c * chanStride);
                rv[c] = *(const float4*)(rp + (size_t)c * chanStride);
            }
        }

        // ---------------- MFMA ----------------
        floatx4 acc[2][5];
        #pragma unroll
        for (int t = 0; t < 2; ++t)
            #pragma unroll
            for (int u = 0; u < 5; ++u)
                #pragma unroll
                for (int r = 0; r < 4; ++r)
                    acc[t][u][r] = 0.0f;

        #pragma unroll
        for (int kk = 0; kk < 2; ++kk) {
            const int col = ((kk * 4 + q) ^ (n & 7)) * 8;
            half8 bfrag[2], afrag[6];
            #pragma unroll
            for (int t = 0; t < 2; ++t)
                bfrag[t] = *(const half8*)&Lb[(wbase + t * 16 + n) * 64 + col];
            #pragma unroll
            for (int a = 0; a < 6; ++a)
                afrag[a] = *(const half8*)&Rb[(wbase + a * 16 + n) * 64 + col];
            #pragma unroll
            for (int t = 0; t < 2; ++t)
                #pragma unroll
                for (int u = 0; u < 5; ++u)
                    acc[t][u] = __builtin_amdgcn_mfma_f32_16x16x32_f16(
                        afrag[t + u], bfrag[t], acc[t][u], 0, 0, 0);
        }
        BAR();   // C: all waves' fragment reads done; Lb/Rb dead

        // acc -> Ob[d][w]. C/D: col = n (w), row m = q*4+r. d = 64-16u+n-m.
        // bank = (4d+w)&31: all 32 banks, 2 lanes each.
        #pragma unroll
        for (int t = 0; t < 2; ++t) {
            const int w = wbase + t * 16 + n;
            #pragma unroll
            for (int u = 0; u < 5; ++u) {
                #pragma unroll
                for (int r = 0; r < 4; ++r) {
                    const int d = 64 - 16 * u + n - (q * 4 + r);
                    if (d >= 0 && d < DD) {
                        Ob[d * OPITCH + w] = acc[t][u][r] * scale;
                    }
                }
            }
        }
        BAR();   // D: Ob complete (lgkmcnt-only)

        // Coalesced stores: wave wv owns d = wv*8 .. wv*8+7; each instruction
        // writes one full 1KB row (lane l at byte offset l*16) — no RFO.
        // These stores drain lazily under the next row's phases.
        #pragma unroll
        for (int i = 0; i < 8; ++i) {
            const int d = wv * 8 + i;
            const float4 v = *(const float4*)&Ob[d * OPITCH + lane * 4];
            *(float4*)&out[(((size_t)b * DD + d) * HH + h) * WW + lane * 4] = v;
        }
    }
}

extern "C" void kernel_launch(void* const* d_in, const int* in_sizes, int n_in,
                              void* d_out, int out_size, void* d_ws, size_t ws_size,
                              hipStream_t stream) {
    const float* left  = (const float*)d_in[0];
    const float* right = (const float*)d_in[1];
    float* out = (float*)d_out;

    dim3 grid(GRID);    // 512 blocks = 2 per CU, each pipelines NROW rows
    dim3 block(512);
    corr_volume_mfma<<<grid, block, 0, stream>>>(left, right, out);
}

// Round 7
// 170.321 us; speedup vs baseline: 1.1344x; 1.0345x over previous
//
#include <hip/hip_runtime.h>

typedef _Float16 half8 __attribute__((ext_vector_type(8)));
typedef float floatx4 __attribute__((ext_vector_type(4)));

#define BB 8
#define CC 64
#define HH 128
#define WW 256
#define DD 64
#define NROW 4            // (b,h) rows per block
#define GRID 256          // 1 block per CU; NROW*GRID == BB*HH
#define OPITCH 260        // Ob row pitch (floats): bank=(4d+w)&31 -> 2 lanes/bank

// LDS-only barrier: all cross-wave data flows through LDS; lgkmcnt(0) is
// sufficient. Prefetch loads and output stores stay in flight across
// barriers (the compiler's "memory" clobber pins issue placement; waits
// are per-thread counted vmcnt at the consuming cvt).
#define BAR() asm volatile("s_waitcnt lgkmcnt(0)\n\ts_barrier" ::: "memory")

// out[b,d,h,w] = (1/64) sum_c L[b,c,h,w] * R[b,c,h,w-d], 0 where w<d.
// Banded Gram via mfma_f32_16x16x32_f16 (d = 64-16u+n-m algebra).
// R7: coalesced LDS-transposed epilogue: 63.5us. R8/R9 restructures: worse.
// R10: lgkm-only barriers: null — with NROW=2 only one row transition is
//     prefetch-covered; the chip stays phase-locked (all blocks load, then
//     all compute, then all store -> HBM duty cycle ~1/3 == measured
//     2.1/6.3 TB/s).
// R11: deepen the pipeline: NROW=4, GRID=256 (1 block/CU). 3 of 4 row
//     loads overlap the previous row's MFMA+transpose+store; exposed
//     prologue burst halves to 32 MB chip-wide. Prefetch issue split
//     around BAR B (lv before, rv after) to spread demand. Output stores
//     are nontemporal so 67 MB/dispatch of output stops evicting the
//     LLC-resident inputs (FETCH_SIZE was 65.6 MB = half the inputs
//     re-fetched every dispatch). (R11b: NT store via ext-vector ptr —
//     __builtin_nontemporal_store rejects HIP_vector_type float4*.)
__global__ __launch_bounds__(512, 2)
void corr_volume_mfma(const float* __restrict__ left,
                      const float* __restrict__ right,
                      float* __restrict__ out) {
    // 72 KiB arena: phase 1 = Lb[256*64] (32K) + Rb[320*64] (40K) halves;
    // phase 2 (epilogue) overlays Ob[64][OPITCH] floats (66,560 B).
    __shared__ alignas(16) unsigned char smem[73728];
    _Float16* const Lb = (_Float16*)smem;
    _Float16* const Rb = (_Float16*)(smem + 32768);
    float*    const Ob = (float*)smem;

    const int tid  = threadIdx.x;
    const int lane = tid & 63;
    const int wv   = tid >> 6;          // wave 0..7
    const int sw   = lane * 4;          // staged w rows sw..sw+3
    const int cg   = wv;                // staged channel group cg*8..cg*8+7

    const size_t chanStride = (size_t)HH * WW;      // 32768

    float4 lv[8], rv[8];

    // Prologue: issue row-0 loads immediately.
    {
        const int bh = blockIdx.x;
        const size_t rowBase = (size_t)(bh >> 7) * CC * chanStride
                             + (size_t)(bh & 127) * WW;
        const float* lp = left  + rowBase + (size_t)(cg * 8) * chanStride + sw;
        const float* rp = right + rowBase + (size_t)(cg * 8) * chanStride + sw;
        #pragma unroll
        for (int c = 0; c < 8; ++c) {
            lv[c] = *(const float4*)(lp + (size_t)c * chanStride);
            rv[c] = *(const float4*)(rp + (size_t)c * chanStride);
        }
    }

    const int n = lane & 15;            // MFMA col (w) / A row
    const int q = lane >> 4;            // quad
    const int wbase = wv * 32;          // this wave's w range
    const float scale = 1.0f / 64.0f;

    #pragma unroll
    for (int k = 0; k < NROW; ++k) {
        const int bh = blockIdx.x + k * GRID;
        const int b  = bh >> 7;
        const int h  = bh & 127;

        BAR();   // A: prior row's Ob ds_reads done (k=0: orders nothing)

        // Re-zero the w'<0 pad rows (Ob overlay clobbers them every row).
        {
            half8 z = {0, 0, 0, 0, 0, 0, 0, 0};
            *(half8*)&Rb[tid * 8] = z;
        }

        // Transpose 8c x 4w from regs -> LDS. Per-thread counted vmcnt
        // waits for this row's loads happen here; no cross-wave drain.
        {
            const float* lf = (const float*)lv;
            const float* rf = (const float*)rv;
            #pragma unroll
            for (int s = 0; s < 4; ++s) {
                const int w   = sw + s;
                const int col = (cg ^ (w & 7)) * 8;
                half8 lh, rh;
                #pragma unroll
                for (int c = 0; c < 8; ++c) {
                    lh[c] = (_Float16)lf[c * 4 + s];
                    rh[c] = (_Float16)rf[c * 4 + s];
                }
                *(half8*)&Lb[w * 64 + col]        = lh;
                *(half8*)&Rb[(w + 64) * 64 + col] = rh;
            }
        }

        // Prefetch next row, L half — issued pre-BAR (regs just freed by
        // the cvt above); stays in flight through MFMA+Ob+stores.
        const float* lp2 = nullptr;
        const float* rp2 = nullptr;
        if (k + 1 < NROW) {
            const int bh2 = blockIdx.x + (k + 1) * GRID;
            const size_t rowBase2 = (size_t)(bh2 >> 7) * CC * chanStride
                                  + (size_t)(bh2 & 127) * WW;
            lp2 = left  + rowBase2 + (size_t)(cg * 8) * chanStride + sw;
            rp2 = right + rowBase2 + (size_t)(cg * 8) * chanStride + sw;
            #pragma unroll
            for (int c = 0; c < 8; ++c)
                lv[c] = *(const float4*)(lp2 + (size_t)c * chanStride);
        }

        BAR();   // B: tiles staged (lgkmcnt-only; loads stay in flight)

        // Prefetch next row, R half — spread issue across the phase.
        if (k + 1 < NROW) {
            #pragma unroll
            for (int c = 0; c < 8; ++c)
                rv[c] = *(const float4*)(rp2 + (size_t)c * chanStride);
        }

        // ---------------- MFMA ----------------
        floatx4 acc[2][5];
        #pragma unroll
        for (int t = 0; t < 2; ++t)
            #pragma unroll
            for (int u = 0; u < 5; ++u)
                #pragma unroll
                for (int r = 0; r < 4; ++r)
                    acc[t][u][r] = 0.0f;

        #pragma unroll
        for (int kk = 0; kk < 2; ++kk) {
            const int col = ((kk * 4 + q) ^ (n & 7)) * 8;
            half8 bfrag[2], afrag[6];
            #pragma unroll
            for (int t = 0; t < 2; ++t)
                bfrag[t] = *(const half8*)&Lb[(wbase + t * 16 + n) * 64 + col];
            #pragma unroll
            for (int a = 0; a < 6; ++a)
                afrag[a] = *(const half8*)&Rb[(wbase + a * 16 + n) * 64 + col];
            #pragma unroll
            for (int t = 0; t < 2; ++t)
                #pragma unroll
                for (int u = 0; u < 5; ++u)
                    acc[t][u] = __builtin_amdgcn_mfma_f32_16x16x32_f16(
                        afrag[t + u], bfrag[t], acc[t][u], 0, 0, 0);
        }
        BAR();   // C: all waves' fragment reads done; Lb/Rb dead

        // acc -> Ob[d][w]. C/D: col = n (w), row m = q*4+r. d = 64-16u+n-m.
        // bank = (4d+w)&31: all 32 banks, 2 lanes each.
        #pragma unroll
        for (int t = 0; t < 2; ++t) {
            const int w = wbase + t * 16 + n;
            #pragma unroll
            for (int u = 0; u < 5; ++u) {
                #pragma unroll
                for (int r = 0; r < 4; ++r) {
                    const int d = 64 - 16 * u + n - (q * 4 + r);
                    if (d >= 0 && d < DD) {
                        Ob[d * OPITCH + w] = acc[t][u][r] * scale;
                    }
                }
            }
        }
        BAR();   // D: Ob complete (lgkmcnt-only)

        // Coalesced nontemporal stores: wave wv owns d = wv*8..wv*8+7; each
        // instruction writes one full 1KB row. NT: don't cache the output —
        // keep the LLC for the inputs. Stores drain lazily under the next
        // row's phases.
        #pragma unroll
        for (int i = 0; i < 8; ++i) {
            const int d = wv * 8 + i;
            const floatx4 v = *(const floatx4*)&Ob[d * OPITCH + lane * 4];
            floatx4* dst = (floatx4*)&out[(((size_t)b * DD + d) * HH + h) * WW + lane * 4];
            __builtin_nontemporal_store(v, dst);
        }
    }
}

extern "C" void kernel_launch(void* const* d_in, const int* in_sizes, int n_in,
                              void* d_out, int out_size, void* d_ws, size_t ws_size,
                              hipStream_t stream) {
    const float* left  = (const float*)d_in[0];
    const float* right = (const float*)d_in[1];
    float* out = (float*)d_out;

    dim3 grid(GRID);    // 256 blocks = 1 per CU, each pipelines NROW rows
    dim3 block(512);
    corr_volume_mfma<<<grid, block, 0, stream>>>(left, right, out);
}

// Round 8
// 169.892 us; speedup vs baseline: 1.1372x; 1.0025x over previous
//
#include <hip/hip_runtime.h>

typedef _Float16 half8 __attribute__((ext_vector_type(8)));
typedef float floatx4 __attribute__((ext_vector_type(4)));

#define BB 8
#define CC 64
#define HH 128
#define WW 256
#define DD 64
#define NROW 4            // (b,h) rows per block
#define GRID 256          // 1 block per CU; NROW*GRID == BB*HH
#define OPITCH 260        // Ob row pitch (floats): bank=(4d+w)&31 -> 2 lanes/bank

// LDS-only barrier: all cross-wave data flows through LDS; lgkmcnt(0) is
// sufficient. Prefetch loads and output stores stay in flight across
// barriers; waits are per-thread counted vmcnt at the consuming cvt.
#define BAR() asm volatile("s_waitcnt lgkmcnt(0)\n\ts_barrier" ::: "memory")

// out[b,d,h,w] = (1/64) sum_c L[b,c,h,w] * R[b,c,h,w-d], 0 where w<d.
// Banded Gram via mfma_f32_16x16x32_f16 (d = 64-16u+n-m algebra).
// R10: lgkm-only barriers (null alone). R11: NROW=4 pipeline + split issue:
//     63.5 -> 58.3us, HBM 2.1 -> 2.3 TB/s. NT stores: null on FETCH_SIZE.
// R12: 2-row-deep register prefetch. Per-CU in-flight was one row's loads
//     (128 KB) while compute+store is only ~0.5us of a ~13us row — waves
//     park at the cvt with the CU idle; at the observed 13 GB/s/CU the
//     implied latency ~10us means we're queue-depth-limited (Little's law).
//     Two statically-indexed register sets (lv/rv[2][8], full unroll ->
//     compile-time indices, no scratch) keep rows k+1 AND k+2 in flight:
//     256 KB/CU outstanding. vmcnt is in-order, so the counted wait for
//     row k+1's regs leaves row k+2's loads in flight (T4, depth 2).
__global__ __launch_bounds__(512, 2)
void corr_volume_mfma(const float* __restrict__ left,
                      const float* __restrict__ right,
                      float* __restrict__ out) {
    // 72 KiB arena: phase 1 = Lb[256*64] (32K) + Rb[320*64] (40K) halves;
    // phase 2 (epilogue) overlays Ob[64][OPITCH] floats (66,560 B).
    __shared__ alignas(16) unsigned char smem[73728];
    _Float16* const Lb = (_Float16*)smem;
    _Float16* const Rb = (_Float16*)(smem + 32768);
    float*    const Ob = (float*)smem;

    const int tid  = threadIdx.x;
    const int lane = tid & 63;
    const int wv   = tid >> 6;          // wave 0..7
    const int sw   = lane * 4;          // staged w rows sw..sw+3
    const int cg   = wv;                // staged channel group cg*8..cg*8+7

    const size_t chanStride = (size_t)HH * WW;      // 32768

    float4 lv[2][8], rv[2][8];          // 2-deep prefetch sets (static idx)

    // Prologue: issue rows 0 and 1 (32 loads/thread in flight).
    #pragma unroll
    for (int p = 0; p < 2; ++p) {
        const int bh = blockIdx.x + p * GRID;
        const size_t rowBase = (size_t)(bh >> 7) * CC * chanStride
                             + (size_t)(bh & 127) * WW;
        const float* lp = left  + rowBase + (size_t)(cg * 8) * chanStride + sw;
        const float* rp = right + rowBase + (size_t)(cg * 8) * chanStride + sw;
        #pragma unroll
        for (int c = 0; c < 8; ++c)
            lv[p][c] = *(const float4*)(lp + (size_t)c * chanStride);
        #pragma unroll
        for (int c = 0; c < 8; ++c)
            rv[p][c] = *(const float4*)(rp + (size_t)c * chanStride);
    }

    const int n = lane & 15;            // MFMA col (w) / A row
    const int q = lane >> 4;            // quad
    const int wbase = wv * 32;          // this wave's w range
    const float scale = 1.0f / 64.0f;

    #pragma unroll
    for (int k = 0; k < NROW; ++k) {
        const int p = k & 1;            // compile-time after unroll
        const int bh = blockIdx.x + k * GRID;
        const int b  = bh >> 7;
        const int h  = bh & 127;

        BAR();   // A: prior row's Ob ds_reads done (k=0: orders nothing)

        // Re-zero the w'<0 pad rows (Ob overlay clobbers them every row).
        {
            half8 z = {0, 0, 0, 0, 0, 0, 0, 0};
            *(half8*)&Rb[tid * 8] = z;
        }

        // Transpose 8c x 4w from regs -> LDS. Counted vmcnt wait lands
        // here (set p only; the other set's 16 loads stay in flight).
        {
            #pragma unroll
            for (int s = 0; s < 4; ++s) {
                const int w   = sw + s;
                const int col = (cg ^ (w & 7)) * 8;
                half8 lh, rh;
                #pragma unroll
                for (int c = 0; c < 8; ++c) {
                    lh[c] = (_Float16)((const float*)&lv[p][c])[s];
                    rh[c] = (_Float16)((const float*)&rv[p][c])[s];
                }
                *(half8*)&Lb[w * 64 + col]        = lh;
                *(half8*)&Rb[(w + 64) * 64 + col] = rh;
            }
        }

        // Refill set p with row k+2 — L half pre-BAR (regs just freed).
        const float* lp2 = nullptr;
        const float* rp2 = nullptr;
        if (k + 2 < NROW) {
            const int bh2 = blockIdx.x + (k + 2) * GRID;
            const size_t rowBase2 = (size_t)(bh2 >> 7) * CC * chanStride
                                  + (size_t)(bh2 & 127) * WW;
            lp2 = left  + rowBase2 + (size_t)(cg * 8) * chanStride + sw;
            rp2 = right + rowBase2 + (size_t)(cg * 8) * chanStride + sw;
            #pragma unroll
            for (int c = 0; c < 8; ++c)
                lv[p][c] = *(const float4*)(lp2 + (size_t)c * chanStride);
        }

        BAR();   // B: tiles staged (lgkmcnt-only; loads stay in flight)

        // Refill set p, R half — spread issue across the phase.
        if (k + 2 < NROW) {
            #pragma unroll
            for (int c = 0; c < 8; ++c)
                rv[p][c] = *(const float4*)(rp2 + (size_t)c * chanStride);
        }

        // ---------------- MFMA ----------------
        floatx4 acc[2][5];
        #pragma unroll
        for (int t = 0; t < 2; ++t)
            #pragma unroll
            for (int u = 0; u < 5; ++u)
                #pragma unroll
                for (int r = 0; r < 4; ++r)
                    acc[t][u][r] = 0.0f;

        #pragma unroll
        for (int kk = 0; kk < 2; ++kk) {
            const int col = ((kk * 4 + q) ^ (n & 7)) * 8;
            half8 bfrag[2], afrag[6];
            #pragma unroll
            for (int t = 0; t < 2; ++t)
                bfrag[t] = *(const half8*)&Lb[(wbase + t * 16 + n) * 64 + col];
            #pragma unroll
            for (int a = 0; a < 6; ++a)
                afrag[a] = *(const half8*)&Rb[(wbase + a * 16 + n) * 64 + col];
            #pragma unroll
            for (int t = 0; t < 2; ++t)
                #pragma unroll
                for (int u = 0; u < 5; ++u)
                    acc[t][u] = __builtin_amdgcn_mfma_f32_16x16x32_f16(
                        afrag[t + u], bfrag[t], acc[t][u], 0, 0, 0);
        }
        BAR();   // C: all waves' fragment reads done; Lb/Rb dead

        // acc -> Ob[d][w]. C/D: col = n (w), row m = q*4+r. d = 64-16u+n-m.
        // bank = (4d+w)&31: all 32 banks, 2 lanes each.
        #pragma unroll
        for (int t = 0; t < 2; ++t) {
            const int w = wbase + t * 16 + n;
            #pragma unroll
            for (int u = 0; u < 5; ++u) {
                #pragma unroll
                for (int r = 0; r < 4; ++r) {
                    const int d = 64 - 16 * u + n - (q * 4 + r);
                    if (d >= 0 && d < DD) {
                        Ob[d * OPITCH + w] = acc[t][u][r] * scale;
                    }
                }
            }
        }
        BAR();   // D: Ob complete (lgkmcnt-only)

        // Coalesced nontemporal stores: wave wv owns d = wv*8..wv*8+7; each
        // instruction writes one full 1KB row. Stores drain lazily under
        // the next row's phases.
        #pragma unroll
        for (int i = 0; i < 8; ++i) {
            const int d = wv * 8 + i;
            const floatx4 v = *(const floatx4*)&Ob[d * OPITCH + lane * 4];
            floatx4* dst = (floatx4*)&out[(((size_t)b * DD + d) * HH + h) * WW + lane * 4];
            __builtin_nontemporal_store(v, dst);
        }
    }
}

extern "C" void kernel_launch(void* const* d_in, const int* in_sizes, int n_in,
                              void* d_out, int out_size, void* d_ws, size_t ws_size,
                              hipStream_t stream) {
    const float* left  = (const float*)d_in[0];
    const float* right = (const float*)d_in[1];
    float* out = (float*)d_out;

    dim3 grid(GRID);    // 256 blocks = 1 per CU, each pipelines NROW rows
    dim3 block(512);
    corr_volume_mfma<<<grid, block, 0, stream>>>(left, right, out);
}